// Round 1
// baseline (16632.600 us; speedup 1.0000x reference)
//
#include <hip/hip_runtime.h>

// ---------------------------------------------------------------------------
// 4-layer tanh RNN, T=256, B=128, H=1024 (fp32 in/out), MI355X gfx950.
//
// Design (round 1):
//  * Single persistent pipelined kernel: 128 blocks = 4 layers x 32 N-tiles
//    (32 output cols each), 512 threads (8 waves) per block.
//  * Fused K=2048 GEMM per step: pre = [x_t | h_{t-1}] @ [Wi; Wh]^T + bias.
//  * Weights live in REGISTERS: each wave owns a (2 n-tiles x 16 k-iters)
//    bf16 fragment set = 128 VGPRs, loaded once, reused for all 256 steps.
//  * Waves = 2 m-halves x 4 K-slices(512). fp32 partials reduced via 64KB LDS,
//    then bias + tanh + bf16 store.
//  * Inter-block sync: per-block progress flags (device-scope atomics),
//    self-timed dataflow; no grid barrier. Ring buffer (8 slots) per layer
//    holds bf16 outputs: slot (t-1)%8 = own h, consumed by layer l+1 as x_t.
//  * MFMA 16x16x32 bf16 with HW-verified layouts:
//      A: m = lane&15, k = (lane>>4)*8 + j
//      B: n = lane&15, k = (lane>>4)*8 + j   (W row-major -> direct 16B loads)
//      C: n = lane&15, m = (lane>>4)*4 + reg
// ---------------------------------------------------------------------------

#define TT 256
#define BB 128
#define HH 1024
#define LL 4
#define RING 8
#define MAT (BB * HH)          // 131072 elements per [B,H] matrix

typedef __attribute__((ext_vector_type(4))) float  float4v;
typedef __attribute__((ext_vector_type(8))) __bf16 bf16x8;
typedef __attribute__((ext_vector_type(8))) unsigned short ushort8;

__device__ inline unsigned short bf16r(float f) {
    union { float f; unsigned u; } v; v.f = f;
    unsigned u = v.u;
    u += 0x7fffu + ((u >> 16) & 1u);     // round-to-nearest-even
    return (unsigned short)(u >> 16);
}

__device__ inline bf16x8 pack8(float4v a, float4v b) {
    ushort8 r;
    r[0] = bf16r(a[0]); r[1] = bf16r(a[1]); r[2] = bf16r(a[2]); r[3] = bf16r(a[3]);
    r[4] = bf16r(b[0]); r[5] = bf16r(b[1]); r[6] = bf16r(b[2]); r[7] = bf16r(b[3]);
    return __builtin_bit_cast(bf16x8, r);
}

__device__ inline float4v mfma16(bf16x8 a, bf16x8 b, float4v c) {
    return __builtin_amdgcn_mfma_f32_16x16x32_bf16(a, b, c, 0, 0, 0);
}

__device__ inline float fast_tanh(float x) {
    float ax = fabsf(x);
    float e  = __expf(-2.0f * ax);
    float r  = (1.0f - e) / (1.0f + e);
    return copysignf(r, x);
}

// --------------------------- prep: flags + h init ---------------------------
__global__ void rnn_prep(const float* __restrict__ hxs,
                         unsigned* __restrict__ F,
                         unsigned short* __restrict__ ring) {
    int i = blockIdx.x * blockDim.x + threadIdx.x;
    if (i < 128) F[i] = 0u;
    int stride = gridDim.x * blockDim.x;
    for (int idx = i; idx < LL * MAT; idx += stride) {
        int g = idx >> 17;            // / MAT
        int rem = idx & (MAT - 1);
        // initial h for layer g -> ring slot RING-1 (read at t=0 as (t-1)%RING)
        ring[(size_t)(g * RING + RING - 1) * MAT + rem] = bf16r(hxs[idx]);
    }
}

// --------------------------- main pipelined kernel --------------------------
__global__ __launch_bounds__(512, 2) void rnn_pipeline(
    const float* __restrict__ xin,   // [T][B][H] fp32
    const float* __restrict__ Wih,   // [L][H][H]
    const float* __restrict__ bih,   // [L][H]
    const float* __restrict__ Whh,   // [L][H][H]
    const float* __restrict__ bhh,   // [L][H]
    float* __restrict__ out,         // [T*B*H + L*B*H]
    unsigned* __restrict__ F,        // [4][32] progress flags
    unsigned short* __restrict__ ring) // [L][RING][B*H] bf16
{
    const int tid  = threadIdx.x;
    const int lane = tid & 63;
    const int wid  = tid >> 6;       // 0..7
    const int ks   = wid & 3;        // K-slice (512 wide): 0,1 = x-half; 2,3 = h-half
    const int mh   = wid >> 2;       // m-half (64 rows)
    const int g    = blockIdx.x >> 5;  // layer
    const int nt   = blockIdx.x & 31;  // n-tile
    const int n0   = nt * 32;

    __shared__ float4v lds_part[8 * 4 * 2 * 64];   // [wid][mt][nt2][lane] = 64KB

    const int rA = lane & 15;        // fragment row/col within tile
    const int qA = lane >> 4;        // quad -> k offset *8

    // ---- load weight fragments into registers (once) ----
    // wave covers global k in [ks*512, ks*512+512); source Wi for ks<2, Wh else
    bf16x8 wfrag[2][16];
    {
        const float* Wsrc = (ks < 2) ? (Wih + (size_t)g * HH * HH)
                                     : (Whh + (size_t)g * HH * HH);
        const int kofs = (ks & 1) * 512;
        for (int nt2 = 0; nt2 < 2; ++nt2) {
            const int n = n0 + nt2 * 16 + rA;
            const float* rowp = Wsrc + (size_t)n * HH + kofs + qA * 8;
            #pragma unroll
            for (int ki = 0; ki < 16; ++ki) {
                float4v f0 = *(const float4v*)(rowp + ki * 32);
                float4v f1 = *(const float4v*)(rowp + ki * 32 + 4);
                wfrag[nt2][ki] = pack8(f0, f1);
            }
        }
    }

    // ---- reduce-phase constants (each thread owns 2 float4-slots) ----
    const int rest0 = tid >> 6;                 // 0..7 (mh bit added via s)
    const int nt2r  = rest0 & 1;
    const int mtr   = (rest0 >> 1) & 3;
    const int l2    = lane;
    const int nr    = n0 + nt2r * 16 + (l2 & 15);
    const float biasv = bih[g * HH + nr] + bhh[g * HH + nr];
    const int mrow0 = mtr * 16 + (l2 >> 4) * 4;

    // ---- A-operand lane offset (element units within a [B,H] matrix) ----
    const int aoff = (mh * 64 + rA) * HH + (ks & 1) * 512 + qA * 8;
    const bool is_x = (ks < 2);

    const unsigned short* ringL = ring + (size_t)g * RING * MAT;
    const unsigned short* ringP = (g > 0) ? ring + (size_t)(g - 1) * RING * MAT : (const unsigned short*)0;
    unsigned short* ringM = ring + (size_t)g * RING * MAT;   // mutable own ring

    for (int t = 0; t < TT; ++t) {
        // -------- wait for dependencies (wave 0 polls, others park) --------
        if (wid == 0) {
            const bool act = lane < 32;
            const unsigned tgt_own = (unsigned)t;
            const unsigned tgt_p   = (unsigned)(t + 1);
            const int tbi = t - RING + 1;
            for (;;) {
                bool ok = true;
                if (act) {
                    unsigned vo = __hip_atomic_load(F + g * 32 + lane,
                                     __ATOMIC_RELAXED, __HIP_MEMORY_SCOPE_AGENT);
                    ok = (vo >= tgt_own);
                    if (ok && g > 0) {
                        unsigned vp = __hip_atomic_load(F + (g - 1) * 32 + lane,
                                         __ATOMIC_RELAXED, __HIP_MEMORY_SCOPE_AGENT);
                        ok = (vp >= tgt_p);
                    }
                    if (ok && g < 3 && tbi > 0) {
                        unsigned vb = __hip_atomic_load(F + (g + 1) * 32 + lane,
                                         __ATOMIC_RELAXED, __HIP_MEMORY_SCOPE_AGENT);
                        ok = (vb >= (unsigned)tbi);
                    }
                }
                if (__ballot(!ok) == 0ull) break;
                __builtin_amdgcn_s_sleep(1);
            }
            __builtin_amdgcn_fence(__ATOMIC_ACQUIRE, "agent");
        }
        __syncthreads();

        // -------- fused GEMM over this wave's K-slice --------
        float4v acc[4][2];
        #pragma unroll
        for (int mt = 0; mt < 4; ++mt) { acc[mt][0] = (float4v)0.0f; acc[mt][1] = (float4v)0.0f; }

        if (is_x && g == 0) {
            const float* xsrc = xin + (size_t)t * MAT;
            for (int ki = 0; ki < 16; ++ki) {
                #pragma unroll
                for (int mt = 0; mt < 4; ++mt) {
                    const float* p = xsrc + aoff + mt * (16 * HH) + ki * 32;
                    float4v f0 = *(const float4v*)p;
                    float4v f1 = *(const float4v*)(p + 4);
                    bf16x8 a = pack8(f0, f1);
                    acc[mt][0] = mfma16(a, wfrag[0][ki], acc[mt][0]);
                    acc[mt][1] = mfma16(a, wfrag[1][ki], acc[mt][1]);
                }
            }
        } else {
            const unsigned short* asrc =
                is_x ? (ringP + (size_t)(t & (RING - 1)) * MAT)          // x from producer layer
                     : (ringL + (size_t)((t + RING - 1) & (RING - 1)) * MAT); // own h
            for (int ki = 0; ki < 16; ++ki) {
                #pragma unroll
                for (int mt = 0; mt < 4; ++mt) {
                    bf16x8 a = *(const bf16x8*)(asrc + aoff + mt * (16 * HH) + ki * 32);
                    acc[mt][0] = mfma16(a, wfrag[0][ki], acc[mt][0]);
                    acc[mt][1] = mfma16(a, wfrag[1][ki], acc[mt][1]);
                }
            }
        }

        // -------- partials -> LDS --------
        #pragma unroll
        for (int mt = 0; mt < 4; ++mt)
            #pragma unroll
            for (int nt2 = 0; nt2 < 2; ++nt2)
                lds_part[((wid * 4 + mt) * 2 + nt2) * 64 + lane] = acc[mt][nt2];
        __syncthreads();

        // -------- reduce 4 K-slices + bias + tanh + stores --------
        unsigned short* ringW = ringM + (size_t)(t & (RING - 1)) * MAT;
        #pragma unroll
        for (int s = 0; s < 2; ++s) {           // s = m-half
            float4v sum = lds_part[(((s * 4 + 0) * 4 + mtr) * 2 + nt2r) * 64 + l2];
            #pragma unroll
            for (int k2 = 1; k2 < 4; ++k2)
                sum += lds_part[(((s * 4 + k2) * 4 + mtr) * 2 + nt2r) * 64 + l2];
            float vals[4];
            #pragma unroll
            for (int r = 0; r < 4; ++r) vals[r] = fast_tanh(sum[r] + biasv);

            const int mb = s * 64 + mrow0;
            const size_t eo = (size_t)mb * HH + nr;
            #pragma unroll
            for (int r = 0; r < 4; ++r) ringW[eo + (size_t)r * HH] = bf16r(vals[r]);
            if (g == 3) {
                float* op = out + (size_t)t * MAT + eo;
                #pragma unroll
                for (int r = 0; r < 4; ++r) op[(size_t)r * HH] = vals[r];
            }
            if (t == TT - 1) {
                float* hp = out + (size_t)TT * MAT + (size_t)g * MAT + eo;
                #pragma unroll
                for (int r = 0; r < 4; ++r) hp[(size_t)r * HH] = vals[r];
            }
        }

        // -------- publish progress --------
        __threadfence();
        __syncthreads();
        if (tid == 0)
            __hip_atomic_store(F + g * 32 + nt, (unsigned)(t + 1),
                               __ATOMIC_RELEASE, __HIP_MEMORY_SCOPE_AGENT);
    }
}

// ------------------------------- launcher -----------------------------------
extern "C" void kernel_launch(void* const* d_in, const int* in_sizes, int n_in,
                              void* d_out, int out_size, void* d_ws, size_t ws_size,
                              hipStream_t stream) {
    const float* xin = (const float*)d_in[0];
    const float* hxs = (const float*)d_in[1];
    const float* Wih = (const float*)d_in[2];
    const float* bih = (const float*)d_in[3];
    const float* Whh = (const float*)d_in[4];
    const float* bhh = (const float*)d_in[5];
    float* out = (float*)d_out;

    unsigned* F = (unsigned*)d_ws;
    unsigned short* ring = (unsigned short*)((char*)d_ws + 1024);
    // ws usage: 1KB flags + 4*8*131072*2B = ~8.4 MB

    rnn_prep<<<256, 256, 0, stream>>>(hxs, F, ring);
    rnn_pipeline<<<128, 512, 0, stream>>>(xin, Wih, bih, Whh, bhh, out, F, ring);
}

// Round 2
// 8426.131 us; speedup vs baseline: 1.9739x; 1.9739x over previous
//
#include <hip/hip_runtime.h>

// ---------------------------------------------------------------------------
// 4-layer tanh RNN, T=256, B=128, H=1024 (fp32 in/out), MI355X gfx950.
//
// Round 2 changes vs round 1 (16.6 ms):
//  * BUG: compute loop over ki was not unrolled -> wfrag[2][16] dynamically
//    indexed -> spilled to scratch (VGPR_Count=60!). Now every wfrag-indexing
//    loop is #pragma unroll; weights truly register-resident (~128 VGPRs).
//  * BUG: per-step __threadfence (buffer_wbl2) + acquire fence (buffer_inv)
//    flushed/invalidated L1+L2 every superstep -> 6.4 GB HBM traffic.
//    Replaced with fence-free protocol: ring data read via inline-asm
//    global_load_dwordx4 sc0 sc1 (device-coherent, reads at L3 coherence
//    point), ring/flag writes via relaxed agent-scope atomics (write-through),
//    ordering via per-wave s_waitcnt vmcnt(0) before the publish barrier.
//  * Coherent-load latency (~700 cyc) hidden with a manual double-buffered
//    vmcnt(4) pipeline (issue ki+1 loads, wait ki, MFMA ki).
// ---------------------------------------------------------------------------

#define TT 256
#define BB 128
#define HH 1024
#define LL 4
#define RING 8
#define MAT (BB * HH)          // 131072 elements per [B,H] matrix

typedef __attribute__((ext_vector_type(4))) float  float4v;
typedef __attribute__((ext_vector_type(4))) unsigned uint4v;
typedef __attribute__((ext_vector_type(8))) __bf16 bf16x8;
typedef __attribute__((ext_vector_type(8))) unsigned short ushort8;

__device__ inline unsigned short bf16r(float f) {
    union { float f; unsigned u; } v; v.f = f;
    unsigned u = v.u;
    u += 0x7fffu + ((u >> 16) & 1u);     // round-to-nearest-even
    return (unsigned short)(u >> 16);
}

__device__ inline bf16x8 pack8(float4v a, float4v b) {
    ushort8 r;
    r[0] = bf16r(a[0]); r[1] = bf16r(a[1]); r[2] = bf16r(a[2]); r[3] = bf16r(a[3]);
    r[4] = bf16r(b[0]); r[5] = bf16r(b[1]); r[6] = bf16r(b[2]); r[7] = bf16r(b[3]);
    return __builtin_bit_cast(bf16x8, r);
}

__device__ inline float4v mfma16(bf16x8 a, bf16x8 b, float4v c) {
    return __builtin_amdgcn_mfma_f32_16x16x32_bf16(a, b, c, 0, 0, 0);
}

__device__ inline float fast_tanh(float x) {
    float ax = fabsf(x);
    float e  = __expf(-2.0f * ax);
    float r  = (1.0f - e) / (1.0f + e);
    return copysignf(r, x);
}

// Device-coherent 16B load (bypasses L1/local-L2; reads at coherence point).
#define GLOADX4(dst, ptr)                                                     \
    asm volatile("global_load_dwordx4 %0, %1, off sc0 sc1"                    \
                 : "=v"(dst) : "v"(ptr))
// Wait until <=4 vm ops outstanding; ties the 4 current-buffer regs so the
// compiler cannot use them before the wait retires.
#define SWAIT4(a, b, c, d)                                                    \
    asm volatile("s_waitcnt vmcnt(4)"                                         \
                 : "+v"(a), "+v"(b), "+v"(c), "+v"(d))
#define SWAIT0(a, b, c, d)                                                    \
    asm volatile("s_waitcnt vmcnt(0)"                                         \
                 : "+v"(a), "+v"(b), "+v"(c), "+v"(d))

// One K-iteration of the ring-sourced GEMM pipeline. CUR holds ki's A-frags
// (in flight since previous step); NXT receives ki+1's loads.
#define GEMM_STEP(ki, CUR, NXT, HASNEXT)                                      \
    {                                                                         \
        if (HASNEXT) {                                                        \
            GLOADX4(NXT[0], abase + ((ki) + 1) * 64 + 0 * 32768);             \
            GLOADX4(NXT[1], abase + ((ki) + 1) * 64 + 1 * 32768);             \
            GLOADX4(NXT[2], abase + ((ki) + 1) * 64 + 2 * 32768);             \
            GLOADX4(NXT[3], abase + ((ki) + 1) * 64 + 3 * 32768);             \
            SWAIT4(CUR[0], CUR[1], CUR[2], CUR[3]);                           \
        } else {                                                              \
            SWAIT0(CUR[0], CUR[1], CUR[2], CUR[3]);                           \
        }                                                                     \
        acc[0][0] = mfma16(__builtin_bit_cast(bf16x8, CUR[0]), wfrag[0][ki], acc[0][0]); \
        acc[0][1] = mfma16(__builtin_bit_cast(bf16x8, CUR[0]), wfrag[1][ki], acc[0][1]); \
        acc[1][0] = mfma16(__builtin_bit_cast(bf16x8, CUR[1]), wfrag[0][ki], acc[1][0]); \
        acc[1][1] = mfma16(__builtin_bit_cast(bf16x8, CUR[1]), wfrag[1][ki], acc[1][1]); \
        acc[2][0] = mfma16(__builtin_bit_cast(bf16x8, CUR[2]), wfrag[0][ki], acc[2][0]); \
        acc[2][1] = mfma16(__builtin_bit_cast(bf16x8, CUR[2]), wfrag[1][ki], acc[2][1]); \
        acc[3][0] = mfma16(__builtin_bit_cast(bf16x8, CUR[3]), wfrag[0][ki], acc[3][0]); \
        acc[3][1] = mfma16(__builtin_bit_cast(bf16x8, CUR[3]), wfrag[1][ki], acc[3][1]); \
    }

// --------------------------- prep: flags + h init ---------------------------
__global__ void rnn_prep(const float* __restrict__ hxs,
                         unsigned* __restrict__ F,
                         unsigned short* __restrict__ ring) {
    int i = blockIdx.x * blockDim.x + threadIdx.x;
    if (i < 128) F[i] = 0u;
    int stride = gridDim.x * blockDim.x;
    for (int idx = i; idx < LL * MAT; idx += stride) {
        int g = idx >> 17;            // / MAT
        int rem = idx & (MAT - 1);
        // initial h for layer g -> ring slot RING-1 (read at t=0 as (t-1)%RING)
        ring[(size_t)(g * RING + RING - 1) * MAT + rem] = bf16r(hxs[idx]);
    }
    // end-of-kernel implicit release flushes these to the coherence point
}

// --------------------------- main pipelined kernel --------------------------
__global__ __launch_bounds__(512, 2) void rnn_pipeline(
    const float* __restrict__ xin,   // [T][B][H] fp32
    const float* __restrict__ Wih,   // [L][H][H]
    const float* __restrict__ bih,   // [L][H]
    const float* __restrict__ Whh,   // [L][H][H]
    const float* __restrict__ bhh,   // [L][H]
    float* __restrict__ out,         // [T*B*H + L*B*H]
    unsigned* __restrict__ F,        // [4][32] progress flags
    unsigned short* __restrict__ ring) // [L][RING][B*H] bf16
{
    const int tid  = threadIdx.x;
    const int lane = tid & 63;
    const int wid  = tid >> 6;       // 0..7
    const int ks   = wid & 3;        // K-slice (512 wide): 0,1 = x-half; 2,3 = h-half
    const int mh   = wid >> 2;       // m-half (64 rows)
    const int g    = blockIdx.x >> 5;  // layer
    const int nt   = blockIdx.x & 31;  // n-tile
    const int n0   = nt * 32;

    __shared__ float4v lds_part[8 * 4 * 2 * 64];   // [wid][mt][nt2][lane] = 64KB

    const int rA = lane & 15;        // fragment row/col within tile
    const int qA = lane >> 4;        // quad -> k offset *8

    // ---- load weight fragments into registers (once) ----
    bf16x8 wfrag[2][16];
    {
        const float* Wsrc = (ks < 2) ? (Wih + (size_t)g * HH * HH)
                                     : (Whh + (size_t)g * HH * HH);
        const int kofs = (ks & 1) * 512;
        #pragma unroll
        for (int nt2 = 0; nt2 < 2; ++nt2) {
            const int n = n0 + nt2 * 16 + rA;
            const float* rowp = Wsrc + (size_t)n * HH + kofs + qA * 8;
            #pragma unroll
            for (int ki = 0; ki < 16; ++ki) {
                float4v f0 = *(const float4v*)(rowp + ki * 32);
                float4v f1 = *(const float4v*)(rowp + ki * 32 + 4);
                wfrag[nt2][ki] = pack8(f0, f1);
            }
        }
    }

    // ---- reduce-phase constants (each thread owns 2 float4-slots) ----
    const int rest0 = tid >> 6;
    const int nt2r  = rest0 & 1;
    const int mtr   = (rest0 >> 1) & 3;
    const int l2    = lane;
    const int nr    = n0 + nt2r * 16 + (l2 & 15);
    const float biasv = bih[g * HH + nr] + bhh[g * HH + nr];
    const int mrow0 = mtr * 16 + (l2 >> 4) * 4;

    // ---- A-operand lane offset (element units within a [B,H] matrix) ----
    const int aoff = (mh * 64 + rA) * HH + (ks & 1) * 512 + qA * 8;
    const bool is_x = (ks < 2);

    const unsigned short* ringL = ring + (size_t)g * RING * MAT;
    const unsigned short* ringP = (g > 0) ? ring + (size_t)(g - 1) * RING * MAT : (const unsigned short*)0;
    unsigned short* ringM = ring + (size_t)g * RING * MAT;

    for (int t = 0; t < TT; ++t) {
        // -------- wait for dependencies (wave 0 polls, others park) --------
        if (wid == 0) {
            const bool act = lane < 32;
            const unsigned tgt_own = (unsigned)t;
            const unsigned tgt_p   = (unsigned)(t + 1);
            const int tbi = t - RING + 1;
            for (;;) {
                bool ok = true;
                if (act) {
                    unsigned vo = __hip_atomic_load(F + g * 32 + lane,
                                     __ATOMIC_RELAXED, __HIP_MEMORY_SCOPE_AGENT);
                    ok = (vo >= tgt_own);
                    if (ok && g > 0) {
                        unsigned vp = __hip_atomic_load(F + (g - 1) * 32 + lane,
                                         __ATOMIC_RELAXED, __HIP_MEMORY_SCOPE_AGENT);
                        ok = (vp >= tgt_p);
                    }
                    if (ok && g < 3 && tbi > 0) {
                        unsigned vb = __hip_atomic_load(F + (g + 1) * 32 + lane,
                                         __ATOMIC_RELAXED, __HIP_MEMORY_SCOPE_AGENT);
                        ok = (vb >= (unsigned)tbi);
                    }
                }
                if (__ballot(!ok) == 0ull) break;
                __builtin_amdgcn_s_sleep(1);
            }
            // no acquire fence needed: all shared-data reads below are sc0/sc1
        }
        __syncthreads();

        // -------- fused GEMM over this wave's K-slice --------
        float4v acc[4][2];
        #pragma unroll
        for (int mt = 0; mt < 4; ++mt) {
            acc[mt][0] = (float4v)0.0f;
            acc[mt][1] = (float4v)0.0f;
        }

        if (is_x && g == 0) {
            // layer-0 x half: plain cached fp32 loads from xin + pack
            const float* xsrc = xin + (size_t)t * MAT;
            #pragma unroll
            for (int ki = 0; ki < 16; ++ki) {
                #pragma unroll
                for (int mt = 0; mt < 4; ++mt) {
                    const float* p = xsrc + aoff + mt * (16 * HH) + ki * 32;
                    float4v f0 = *(const float4v*)p;
                    float4v f1 = *(const float4v*)(p + 4);
                    bf16x8 a = pack8(f0, f1);
                    acc[mt][0] = mfma16(a, wfrag[0][ki], acc[mt][0]);
                    acc[mt][1] = mfma16(a, wfrag[1][ki], acc[mt][1]);
                }
            }
        } else {
            // ring-sourced half: device-coherent loads, vmcnt-pipelined
            const unsigned short* asrc =
                is_x ? (ringP + (size_t)(t & (RING - 1)) * MAT)
                     : (ringL + (size_t)((t + RING - 1) & (RING - 1)) * MAT);
            const char* abase = (const char*)(asrc + aoff);
            uint4v b0[4], b1[4];
            GLOADX4(b0[0], abase + 0 * 32768);
            GLOADX4(b0[1], abase + 1 * 32768);
            GLOADX4(b0[2], abase + 2 * 32768);
            GLOADX4(b0[3], abase + 3 * 32768);
            #pragma unroll
            for (int kp = 0; kp < 8; ++kp) {
                GEMM_STEP(2 * kp,     b0, b1, true);
                GEMM_STEP(2 * kp + 1, b1, b0, (kp < 7));
            }
        }

        // -------- partials -> LDS --------
        #pragma unroll
        for (int mt = 0; mt < 4; ++mt)
            #pragma unroll
            for (int nt2 = 0; nt2 < 2; ++nt2)
                lds_part[((wid * 4 + mt) * 2 + nt2) * 64 + lane] = acc[mt][nt2];
        __syncthreads();

        // -------- reduce 4 K-slices + bias + tanh + stores --------
        unsigned short* ringW = ringM + (size_t)(t & (RING - 1)) * MAT;
        #pragma unroll
        for (int s = 0; s < 2; ++s) {           // s = m-half
            float4v sum = lds_part[(((s * 4 + 0) * 4 + mtr) * 2 + nt2r) * 64 + l2];
            #pragma unroll
            for (int k2 = 1; k2 < 4; ++k2)
                sum += lds_part[(((s * 4 + k2) * 4 + mtr) * 2 + nt2r) * 64 + l2];
            float vals[4];
            #pragma unroll
            for (int r = 0; r < 4; ++r) vals[r] = fast_tanh(sum[r] + biasv);

            const int mb = s * 64 + mrow0;
            const size_t eo = (size_t)mb * HH + nr;
            // ring publish: relaxed agent-scope (write-through to coherence pt)
            #pragma unroll
            for (int r = 0; r < 4; ++r)
                __hip_atomic_store(ringW + eo + (size_t)r * HH, bf16r(vals[r]),
                                   __ATOMIC_RELAXED, __HIP_MEMORY_SCOPE_AGENT);
            if (g == 3) {
                float* op = out + (size_t)t * MAT + eo;
                #pragma unroll
                for (int r = 0; r < 4; ++r) op[(size_t)r * HH] = vals[r];
            }
            if (t == TT - 1) {
                float* hp = out + (size_t)TT * MAT + (size_t)g * MAT + eo;
                #pragma unroll
                for (int r = 0; r < 4; ++r) hp[(size_t)r * HH] = vals[r];
            }
        }

        // -------- publish progress (no cache flush) --------
        // Drain this wave's ring stores to the coherence point, then barrier
        // (all waves drained), then a single relaxed flag store.
        asm volatile("s_waitcnt vmcnt(0)" ::: "memory");
        __syncthreads();
        if (tid == 0)
            __hip_atomic_store(F + g * 32 + nt, (unsigned)(t + 1),
                               __ATOMIC_RELAXED, __HIP_MEMORY_SCOPE_AGENT);
    }
}

// ------------------------------- launcher -----------------------------------
extern "C" void kernel_launch(void* const* d_in, const int* in_sizes, int n_in,
                              void* d_out, int out_size, void* d_ws, size_t ws_size,
                              hipStream_t stream) {
    const float* xin = (const float*)d_in[0];
    const float* hxs = (const float*)d_in[1];
    const float* Wih = (const float*)d_in[2];
    const float* bih = (const float*)d_in[3];
    const float* Whh = (const float*)d_in[4];
    const float* bhh = (const float*)d_in[5];
    float* out = (float*)d_out;

    unsigned* F = (unsigned*)d_ws;
    unsigned short* ring = (unsigned short*)((char*)d_ws + 1024);
    // ws usage: 1KB flags + 4*8*131072*2B = ~8.4 MB

    rnn_prep<<<256, 256, 0, stream>>>(hxs, F, ring);
    rnn_pipeline<<<128, 512, 0, stream>>>(xin, Wih, bih, Whh, bhh, out, F, ring);
}